// Round 1
// baseline (77.849 us; speedup 1.0000x reference)
//
#include <hip/hip_runtime.h>

// Problem constants (B,N,M,K) = (4, 512, 512, 256)
constexpr int Mdim = 512;    // inner (reduction) dim
constexpr int Kdim = 256;    // output columns (= w rows)
constexpr int ROWS = 2048;   // B*N flattened x rows
constexpr int TILE_R = 8;    // x rows per block in gemm kernel
constexpr int MW = Mdim / 4; // 128 packed int8 words per row

// Safe across-arch dot4 (device-libs, inlines to v_dot4_i32_i8 where available)
extern "C" __device__ int __ockl_sdot4(int, int, int, bool);
__device__ __forceinline__ int dot4(int a, int b, int c) {
    return __ockl_sdot4(a, b, c, false);
}

__device__ __forceinline__ int qz(float v, float scale, float zp) {
    float q = rintf(v / scale + zp);          // matches jnp.round(t/scale + zp), half-to-even
    q = fminf(fmaxf(q, -128.0f), 127.0f);     // clip
    return (int)q;
}

__device__ __forceinline__ int pack4(int q0, int q1, int q2, int q3) {
    return (q0 & 255) | ((q1 & 255) << 8) | ((q2 & 255) << 16) | ((q3 & 255) << 24);
}

// One block (64 threads = 1 wave) per w row k.
// Packs wq into transposed layout: int4 per (quad q, col k) at wq4[q*Kdim + k],
// where quad q covers m in [q*16, q*16+16). Also writes wsum[k] = sum_m wq[k,m].
__global__ __launch_bounds__(64) void quant_w_kernel(
        const float* __restrict__ w,
        const float* __restrict__ w_scale, const float* __restrict__ w_zp,
        int* __restrict__ wq_t, int* __restrict__ wsum) {
    const int k = blockIdx.x;
    const int tid = threadIdx.x;
    const float s = w_scale[0], zp = w_zp[0];

    const float4* wrow = (const float4*)(w + (size_t)k * Mdim);
    float4 a = wrow[tid * 2];
    float4 b = wrow[tid * 2 + 1];

    int q0 = qz(a.x, s, zp), q1 = qz(a.y, s, zp), q2 = qz(a.z, s, zp), q3 = qz(a.w, s, zp);
    int q4 = qz(b.x, s, zp), q5 = qz(b.y, s, zp), q6 = qz(b.z, s, zp), q7 = qz(b.w, s, zp);

    int w0 = pack4(q0, q1, q2, q3);
    int w1 = pack4(q4, q5, q6, q7);

    // word index wi = 2*tid + j ; quad = wi>>2 ; sub = wi&3
    const int wi0 = 2 * tid;
    const int quad = wi0 >> 2;
    const int sub = wi0 & 3;
    *(int2*)&wq_t[((size_t)quad * Kdim + k) * 4 + sub] = make_int2(w0, w1);

    int sum = q0 + q1 + q2 + q3 + q4 + q5 + q6 + q7;
    #pragma unroll
    for (int off = 32; off > 0; off >>= 1) sum += __shfl_down(sum, off);
    if (tid == 0) wsum[k] = sum;
}

// One block (256 threads) per TILE_R x-rows. Thread t owns output column k=t.
__global__ __launch_bounds__(256) void lut_gemm_kernel(
        const float* __restrict__ x,
        const int* __restrict__ wq_t, const int* __restrict__ wsum,
        const float* __restrict__ x_scale, const float* __restrict__ x_zp,
        const float* __restrict__ w_scale, const float* __restrict__ w_zp,
        float* __restrict__ out) {
    __shared__ __align__(16) int x_lds[TILE_R * MW];  // 1024 words = 4 KB
    __shared__ int xsum[TILE_R];

    const int t = threadIdx.x;
    const int r0 = blockIdx.x * TILE_R;

    if (t < TILE_R) xsum[t] = 0;
    __syncthreads();

    const float xs = x_scale[0], xzpf = x_zp[0];
    const float wsf = w_scale[0], wzpf = w_zp[0];

    // Stage + quantize x tile: 8 rows x 512 = 1024 packed words.
    const float4* xrow4 = (const float4*)(x + (size_t)r0 * Mdim);
    #pragma unroll
    for (int i = 0; i < 4; ++i) {
        const int wi = i * 256 + t;          // flat word index [row][mword]
        float4 f = xrow4[wi];                // fully coalesced
        int q0 = qz(f.x, xs, xzpf), q1 = qz(f.y, xs, xzpf);
        int q2 = qz(f.z, xs, xzpf), q3 = qz(f.w, xs, xzpf);
        x_lds[wi] = pack4(q0, q1, q2, q3);   // stride-1 words: conflict-free
        int s = q0 + q1 + q2 + q3;
        // each wave's 64 lanes fall in a single row this iteration -> wave reduce
        #pragma unroll
        for (int off = 32; off > 0; off >>= 1) s += __shfl_down(s, off);
        if ((t & 63) == 0) atomicAdd(&xsum[wi >> 7], s);
    }
    __syncthreads();

    const int k = t;  // 256 threads == Kdim columns
    int acc[TILE_R];
    #pragma unroll
    for (int r = 0; r < TILE_R; ++r) acc[r] = 0;

    const int4* wq4 = (const int4*)wq_t;
    #pragma unroll 4
    for (int q = 0; q < MW / 4; ++q) {       // 32 iterations, 16 m-elems each
        const int4 wv = wq4[(size_t)q * Kdim + k];   // coalesced 16B/lane
        #pragma unroll
        for (int r = 0; r < TILE_R; ++r) {
            const int4 xv = *(const int4*)&x_lds[r * MW + q * 4];  // broadcast (free)
            acc[r] = dot4(xv.x, wv.x, acc[r]);
            acc[r] = dot4(xv.y, wv.y, acc[r]);
            acc[r] = dot4(xv.z, wv.z, acc[r]);
            acc[r] = dot4(xv.w, wv.w, acc[r]);
        }
    }

    // Epilogue: acc - wzp*xsum[row] - xzp*wsum[k] + M*xzp*wzp, scaled by xs*ws
    const float wsumk = (float)wsum[k];
    const float corr_const = (float)Mdim * xzpf * wzpf - xzpf * wsumk;
    const float oscale = xs * wsf;
    #pragma unroll
    for (int r = 0; r < TILE_R; ++r) {
        float a = (float)acc[r] - wzpf * (float)xsum[r] + corr_const;
        out[(size_t)(r0 + r) * Kdim + k] = a * oscale;  // coalesced stores
    }
}

extern "C" void kernel_launch(void* const* d_in, const int* in_sizes, int n_in,
                              void* d_out, int out_size, void* d_ws, size_t ws_size,
                              hipStream_t stream) {
    const float* x       = (const float*)d_in[0];
    const float* w       = (const float*)d_in[1];
    // d_in[2] = lut: unused (lut[xi,wi] == signed(xi)*signed(wi), computed directly)
    const float* x_scale = (const float*)d_in[3];
    const float* x_zp    = (const float*)d_in[4];
    const float* w_scale = (const float*)d_in[5];
    const float* w_zp    = (const float*)d_in[6];
    float* out = (float*)d_out;

    int* wq_t = (int*)d_ws;               // Kdim*MW = 32768 ints (128 KB)
    int* wsum = wq_t + Kdim * MW;         // 256 ints

    quant_w_kernel<<<Kdim, 64, 0, stream>>>(w, w_scale, w_zp, wq_t, wsum);
    lut_gemm_kernel<<<ROWS / TILE_R, 256, 0, stream>>>(
        x, wq_t, wsum, x_scale, x_zp, w_scale, w_zp, out);
}

// Round 2
// 75.559 us; speedup vs baseline: 1.0303x; 1.0303x over previous
//
#include <hip/hip_runtime.h>

// (B,N,M,K) = (4,512,512,256): out[2048,256] = xq[2048,512]·wq[256,512]^T  (int8 dots)
constexpr int Mdim = 512;
constexpr int Kdim = 256;
constexpr int ROWS = 2048;
constexpr int MW   = Mdim / 4;   // 128 packed words per row
constexpr int R_PB = 4;          // rows per gemm block

// ws layout (in ints):
//   xq   : [0, 262144)          2048 rows x 128 words (1 MB), row-major
//   wq_t : [262144, 294912)     transposed: int4 unit at [quad*Kdim + k]
//   xsum : [294912, 296960)
//   wsum : [296960, 297216)
constexpr int XQ_OFF   = 0;
constexpr int WQT_OFF  = 262144;
constexpr int XSUM_OFF = 294912;
constexpr int WSUM_OFF = 296960;

extern "C" __device__ int __ockl_sdot4(int, int, int, bool);
__device__ __forceinline__ int dot4(int a, int b, int c) {
    return __ockl_sdot4(a, b, c, false);
}

__device__ __forceinline__ int qz(float v, float scale, float zp) {
    float q = rintf(v / scale + zp);          // exact: matches jnp.round(t/scale + zp)
    q = fminf(fmaxf(q, -128.0f), 127.0f);
    return (int)q;
}

__device__ __forceinline__ int pack4(int q0, int q1, int q2, int q3) {
    return (q0 & 255) | ((q1 & 255) << 8) | ((q2 & 255) << 16) | ((q3 & 255) << 24);
}

// Fused quantize: blocks [0,2048) quantize x rows; blocks [2048,2304) quantize w rows.
// One wave per row, 8 floats per thread.
__global__ __launch_bounds__(64) void quant_kernel(
        const float* __restrict__ x, const float* __restrict__ w,
        const float* __restrict__ x_scale, const float* __restrict__ x_zp,
        const float* __restrict__ w_scale, const float* __restrict__ w_zp,
        int* __restrict__ ws) {
    const int tid = threadIdx.x;
    const bool is_x = (blockIdx.x < ROWS);
    const int row = is_x ? blockIdx.x : (blockIdx.x - ROWS);
    const float s  = is_x ? x_scale[0] : w_scale[0];
    const float zp = is_x ? x_zp[0]    : w_zp[0];
    const float* src = (is_x ? x : w) + (size_t)row * Mdim;

    const float4* src4 = (const float4*)src;
    float4 a = src4[tid * 2];
    float4 b = src4[tid * 2 + 1];

    int q0 = qz(a.x, s, zp), q1 = qz(a.y, s, zp), q2 = qz(a.z, s, zp), q3 = qz(a.w, s, zp);
    int q4 = qz(b.x, s, zp), q5 = qz(b.y, s, zp), q6 = qz(b.z, s, zp), q7 = qz(b.w, s, zp);
    int w0 = pack4(q0, q1, q2, q3);
    int w1 = pack4(q4, q5, q6, q7);

    if (is_x) {
        // row-major packed: coalesced int2 stores
        *(int2*)&ws[XQ_OFF + row * MW + 2 * tid] = make_int2(w0, w1);
    } else {
        // transposed: int4 unit [quad*Kdim + k], word sub = wi&3
        const int wi0 = 2 * tid;
        const int quad = wi0 >> 2;
        const int sub  = wi0 & 3;
        *(int2*)&ws[WQT_OFF + ((size_t)quad * Kdim + row) * 4 + sub] = make_int2(w0, w1);
    }

    int sum = q0 + q1 + q2 + q3 + q4 + q5 + q6 + q7;
    #pragma unroll
    for (int off = 32; off > 0; off >>= 1) sum += __shfl_down(sum, off);
    if (tid == 0) ws[(is_x ? XSUM_OFF : WSUM_OFF) + row] = sum;
}

// 512 blocks x 512 threads. Thread t: column k = t&255, M-half h = t>>8.
// W half-row lives in 16 int4 VGPRs; x streamed via wave-uniform loads.
__global__ __launch_bounds__(512, 4) void lut_gemm_kernel(
        const int* __restrict__ ws,
        const float* __restrict__ x_scale, const float* __restrict__ x_zp,
        const float* __restrict__ w_scale, const float* __restrict__ w_zp,
        float* __restrict__ out) {
    __shared__ int accs[R_PB][Kdim];   // h=1 partials (4 KB)

    const int t = threadIdx.x;
    const int k = t & (Kdim - 1);
    const int hu = __builtin_amdgcn_readfirstlane(t >> 8);  // wave-uniform half index
    const int r0 = blockIdx.x * R_PB;

    // Load this thread's w half-row: quads [hu*16, hu*16+16), coalesced over k.
    const int4* wq4 = (const int4*)&ws[WQT_OFF];
    int4 wv[16];
    #pragma unroll
    for (int q = 0; q < 16; ++q)
        wv[q] = wq4[(size_t)(hu * 16 + q) * Kdim + k];

    int acc[R_PB];
    #pragma unroll
    for (int r = 0; r < R_PB; ++r) acc[r] = 0;

    const int4* xq4 = (const int4*)&ws[XQ_OFF];
    #pragma unroll
    for (int r = 0; r < R_PB; ++r) {
        const int4* xb = xq4 + (size_t)(r0 + r) * (MW / 4) + hu * 16;  // wave-uniform
        #pragma unroll
        for (int q = 0; q < 16; ++q) {
            int4 xv = xb[q];
            acc[r] = dot4(xv.x, wv[q].x, acc[r]);
            acc[r] = dot4(xv.y, wv[q].y, acc[r]);
            acc[r] = dot4(xv.z, wv[q].z, acc[r]);
            acc[r] = dot4(xv.w, wv[q].w, acc[r]);
        }
    }

    if (hu == 1) {
        #pragma unroll
        for (int r = 0; r < R_PB; ++r) accs[r][k] = acc[r];
    }
    __syncthreads();
    if (hu == 0) {
        const float xs = x_scale[0], xzpf = x_zp[0];
        const float wsf = w_scale[0], wzpf = w_zp[0];
        const float wsumk = (float)ws[WSUM_OFF + k];
        const float corr_const = (float)Mdim * xzpf * wzpf - xzpf * wsumk;
        const float oscale = xs * wsf;
        #pragma unroll
        for (int r = 0; r < R_PB; ++r) {
            int total = acc[r] + accs[r][k];
            float xsumr = (float)ws[XSUM_OFF + (r0 + r)];
            float v = (float)total - wzpf * xsumr + corr_const;
            out[(size_t)(r0 + r) * Kdim + k] = v * oscale;   // coalesced
        }
    }
}

extern "C" void kernel_launch(void* const* d_in, const int* in_sizes, int n_in,
                              void* d_out, int out_size, void* d_ws, size_t ws_size,
                              hipStream_t stream) {
    const float* x       = (const float*)d_in[0];
    const float* w       = (const float*)d_in[1];
    // d_in[2] = lut: unused (lut[xi,wi] == signed(xi)*signed(wi))
    const float* x_scale = (const float*)d_in[3];
    const float* x_zp    = (const float*)d_in[4];
    const float* w_scale = (const float*)d_in[5];
    const float* w_zp    = (const float*)d_in[6];
    float* out = (float*)d_out;
    int* ws = (int*)d_ws;

    quant_kernel<<<ROWS + Kdim, 64, 0, stream>>>(x, w, x_scale, x_zp, w_scale, w_zp, ws);
    lut_gemm_kernel<<<ROWS / R_PB, 512, 0, stream>>>(ws, x_scale, x_zp, w_scale, w_zp, out);
}

// Round 3
// 72.795 us; speedup vs baseline: 1.0694x; 1.0380x over previous
//
#include <hip/hip_runtime.h>

// (B,N,M,K) = (4,512,512,256): out[2048,256] = xq[2048,512]·wq[256,512]^T (int8)
constexpr int Mdim = 512;
constexpr int Kdim = 256;
constexpr int ROWS = 2048;
constexpr int MW   = Mdim / 4;   // 128 packed int8-words per row

// ws layout (ints):
constexpr int XQ_OFF   = 0;                      // 2048 x 128 words, row-major
constexpr int WQ_OFF   = ROWS * MW;              // 262144: 256 x 128 words, row-major
constexpr int XSUM_OFF = WQ_OFF + Kdim * MW;     // 294912
constexpr int WSUM_OFF = XSUM_OFF + ROWS;        // 296960

typedef int v4i __attribute__((ext_vector_type(4)));

__device__ __forceinline__ int qz(float v, float scale, float zp) {
    float q = rintf(v / scale + zp);          // matches jnp.round(t/scale + zp)
    q = fminf(fmaxf(q, -128.0f), 127.0f);
    return (int)q;
}

__device__ __forceinline__ int pack4(int q0, int q1, int q2, int q3) {
    return (q0 & 255) | ((q1 & 255) << 8) | ((q2 & 255) << 16) | ((q3 & 255) << 24);
}

// Blocks [0,2048): x rows; [2048,2304): w rows. One wave/row, 8 floats/thread.
// Row-major packed output for both (MFMA fragments are direct int4 loads).
__global__ __launch_bounds__(64) void quant_kernel(
        const float* __restrict__ x, const float* __restrict__ w,
        const float* __restrict__ x_scale, const float* __restrict__ x_zp,
        const float* __restrict__ w_scale, const float* __restrict__ w_zp,
        int* __restrict__ ws) {
    const int tid = threadIdx.x;
    const bool is_x = (blockIdx.x < ROWS);
    const int row = is_x ? blockIdx.x : (blockIdx.x - ROWS);
    const float s  = is_x ? x_scale[0] : w_scale[0];
    const float zp = is_x ? x_zp[0]    : w_zp[0];
    const float* src = (is_x ? x : w) + (size_t)row * Mdim;

    const float4* src4 = (const float4*)src;
    float4 a = src4[tid * 2];
    float4 b = src4[tid * 2 + 1];

    int q0 = qz(a.x, s, zp), q1 = qz(a.y, s, zp), q2 = qz(a.z, s, zp), q3 = qz(a.w, s, zp);
    int q4 = qz(b.x, s, zp), q5 = qz(b.y, s, zp), q6 = qz(b.z, s, zp), q7 = qz(b.w, s, zp);

    const int base = (is_x ? XQ_OFF : WQ_OFF) + row * MW + 2 * tid;
    *(int2*)&ws[base] = make_int2(pack4(q0, q1, q2, q3), pack4(q4, q5, q6, q7));

    int sum = q0 + q1 + q2 + q3 + q4 + q5 + q6 + q7;
    #pragma unroll
    for (int off = 32; off > 0; off >>= 1) sum += __shfl_down(sum, off);
    if (tid == 0) ws[(is_x ? XSUM_OFF : WSUM_OFF) + row] = sum;
}

// One wave per 16x16 output tile. 2048 blocks x 64 threads.
// A frag: lane l holds xq[r0 + (l&15)][bytes kk*64 + (l>>4)*16 .. +16)
// B frag: lane l holds wq[c0 + (l&15)][same byte window]   (wq row-major == W^T cols)
// D: col = c0 + (l&15), row = r0 + (l>>4)*4 + reg
__global__ __launch_bounds__(64) void mfma_gemm_kernel(
        const int* __restrict__ ws,
        const float* __restrict__ x_scale, const float* __restrict__ x_zp,
        const float* __restrict__ w_scale, const float* __restrict__ w_zp,
        float* __restrict__ out) {
    const int lane  = threadIdx.x;
    const int group = lane >> 4;
    const int lo    = lane & 15;
    const int r0 = (blockIdx.x >> 4) * 16;   // 128 row-tiles
    const int c0 = (blockIdx.x & 15) * 16;   // 16 col-tiles

    const v4i* xa = (const v4i*)&ws[XQ_OFF + (size_t)(r0 + lo) * MW];
    const v4i* wb = (const v4i*)&ws[WQ_OFF + (size_t)(c0 + lo) * MW];

    v4i a[8], b[8];
    #pragma unroll
    for (int kk = 0; kk < 8; ++kk) {        // 16 int4 loads in flight
        a[kk] = xa[kk * 4 + group];
        b[kk] = wb[kk * 4 + group];
    }

    v4i acc = {0, 0, 0, 0};
    #pragma unroll
    for (int kk = 0; kk < 8; ++kk)
        acc = __builtin_amdgcn_mfma_i32_16x16x64_i8(a[kk], b[kk], acc, 0, 0, 0);

    const float xs = x_scale[0], xzpf = x_zp[0];
    const float wsf = w_scale[0], wzpf = w_zp[0];
    const float wsumc = (float)ws[WSUM_OFF + c0 + lo];
    const v4i xs4 = *(const v4i*)&ws[XSUM_OFF + r0 + group * 4];  // 16B-aligned
    const float corr = (float)Mdim * xzpf * wzpf - xzpf * wsumc;
    const float oscale = xs * wsf;

    #pragma unroll
    for (int i = 0; i < 4; ++i) {
        const int row = r0 + group * 4 + i;
        float v = (float)acc[i] - wzpf * (float)xs4[i] + corr;
        out[(size_t)row * Kdim + c0 + lo] = v * oscale;
    }
}

extern "C" void kernel_launch(void* const* d_in, const int* in_sizes, int n_in,
                              void* d_out, int out_size, void* d_ws, size_t ws_size,
                              hipStream_t stream) {
    const float* x       = (const float*)d_in[0];
    const float* w       = (const float*)d_in[1];
    // d_in[2] = lut: unused (lut[xi,wi] == signed(xi)*signed(wi))
    const float* x_scale = (const float*)d_in[3];
    const float* x_zp    = (const float*)d_in[4];
    const float* w_scale = (const float*)d_in[5];
    const float* w_zp    = (const float*)d_in[6];
    float* out = (float*)d_out;
    int* ws = (int*)d_ws;

    quant_kernel<<<ROWS + Kdim, 64, 0, stream>>>(x, w, x_scale, x_zp, w_scale, w_zp, ws);
    mfma_gemm_kernel<<<(ROWS / 16) * (Kdim / 16), 64, 0, stream>>>(
        ws, x_scale, x_zp, w_scale, w_zp, out);
}